// Round 5
// baseline (554.498 us; speedup 1.0000x reference)
//
#include <hip/hip_runtime.h>
#include <hip/hip_bf16.h>

#define BB 4096
#define DD 1024
#define NBF 16
#define HH 2048
#define KK 16384   // DD*NBF
#define NT 256     // K-tiles of 64
#define LN_EPS 1e-5f

typedef short bs8 __attribute__((ext_vector_type(8)));            // 8 bf16 (MFMA A/B frag)
typedef unsigned short us8 __attribute__((ext_vector_type(8)));   // 8 bf16 store
typedef float f32x4 __attribute__((ext_vector_type(4)));          // MFMA C/D frag

__device__ __forceinline__ unsigned short f2bf(float f) {
  union { float f; unsigned int u; } c; c.f = f;
  unsigned int u = c.u;
  return (unsigned short)((u + 0x7FFFu + ((u >> 16) & 1u)) >> 16);  // RNE
}
__device__ __forceinline__ float bf2f(unsigned short s) {
  union { unsigned int u; float f; } c; c.u = ((unsigned int)s) << 16;
  return c.f;
}
__device__ __forceinline__ float softplusf(float x) {
  return (x > 20.f) ? x : log1pf(expf(x));
}

// cs[d*16+k] = centers[d][k] / (softplus(width[d]) + 1e-6)
__global__ void prep_kernel(const float* __restrict__ centers, const float* __restrict__ width,
                            float* __restrict__ cs) {
  const int i = blockIdx.x * 256 + threadIdx.x;  // 16384 total
  const int d = i >> 4;
  const float w = softplusf(width[d]) + 1e-6f;
  cs[i] = centers[i] / w;
}

// LayerNorm + triangular-basis expansion -> z (bf16 [B,KK]), and ylin[b]
__global__ __launch_bounds__(256)
void zexp_kernel(const float* __restrict__ x, const float* __restrict__ g,
                 const float* __restrict__ be, const float* __restrict__ width,
                 const float* __restrict__ sh_w, const float* __restrict__ sh_b,
                 const float* __restrict__ cs,
                 unsigned short* __restrict__ z, float* __restrict__ ylin) {
  __shared__ float red[8];
  const int b = blockIdx.x, tid = threadIdx.x;
  const float4 v = ((const float4*)(x + (size_t)b * DD))[tid];
  float s  = v.x + v.y + v.z + v.w;
  float ss = v.x*v.x + v.y*v.y + v.z*v.z + v.w*v.w;
  #pragma unroll
  for (int off = 32; off > 0; off >>= 1) {
    s  += __shfl_xor(s, off);
    ss += __shfl_xor(ss, off);
  }
  if ((tid & 63) == 0) { red[(tid>>6)*2] = s; red[(tid>>6)*2+1] = ss; }
  __syncthreads();
  const float sum   = red[0]+red[2]+red[4]+red[6];
  const float sumsq = red[1]+red[3]+red[5]+red[7];
  const float mu   = sum * (1.f/DD);
  const float var  = sumsq * (1.f/DD) - mu*mu;
  const float rstd = rsqrtf(var + LN_EPS);
  const float4 g4 = ((const float4*)g)[tid];
  const float4 b4 = ((const float4*)be)[tid];
  const float4 w4 = ((const float4*)width)[tid];
  const float4 s4 = ((const float4*)sh_w)[tid];
  const float xn0 = (v.x - mu)*rstd*g4.x + b4.x;
  const float xn1 = (v.y - mu)*rstd*g4.y + b4.y;
  const float xn2 = (v.z - mu)*rstd*g4.z + b4.z;
  const float xn3 = (v.w - mu)*rstd*g4.w + b4.w;
  float xsv[4];
  xsv[0] = xn0 / (softplusf(w4.x) + 1e-6f);
  xsv[1] = xn1 / (softplusf(w4.y) + 1e-6f);
  xsv[2] = xn2 / (softplusf(w4.z) + 1e-6f);
  xsv[3] = xn3 / (softplusf(w4.w) + 1e-6f);
  unsigned short* zr = z + (size_t)b * KK + tid * 64;
  #pragma unroll
  for (int j = 0; j < 4; ++j) {
    const float4* c4 = (const float4*)(cs + (tid * 4 + j) * 16);
    const float xv = xsv[j];
    us8 o0, o1;
    #pragma unroll
    for (int q = 0; q < 2; ++q) {
      const float4 ca = c4[q*2], cb = c4[q*2+1];
      us8& o = q ? o1 : o0;
      o[0] = f2bf(fmaxf(0.f, 1.f - fabsf(xv - ca.x)));
      o[1] = f2bf(fmaxf(0.f, 1.f - fabsf(xv - ca.y)));
      o[2] = f2bf(fmaxf(0.f, 1.f - fabsf(xv - ca.z)));
      o[3] = f2bf(fmaxf(0.f, 1.f - fabsf(xv - ca.w)));
      o[4] = f2bf(fmaxf(0.f, 1.f - fabsf(xv - cb.x)));
      o[5] = f2bf(fmaxf(0.f, 1.f - fabsf(xv - cb.y)));
      o[6] = f2bf(fmaxf(0.f, 1.f - fabsf(xv - cb.z)));
      o[7] = f2bf(fmaxf(0.f, 1.f - fabsf(xv - cb.w)));
    }
    ((us8*)(zr + j * 16))[0] = o0;
    ((us8*)(zr + j * 16))[1] = o1;
  }
  float yd = xn0*s4.x + xn1*s4.y + xn2*s4.z + xn3*s4.w;
  #pragma unroll
  for (int off = 32; off > 0; off >>= 1) yd += __shfl_xor(yd, off);
  __syncthreads();
  if ((tid & 63) == 0) red[tid>>6] = yd;
  __syncthreads();
  if (tid == 0) ylin[b] = red[0]+red[1]+red[2]+red[3] + sh_b[0];
}

// fc1_w fp32 -> bf16
__global__ void cvt_kernel(const float* __restrict__ w, unsigned short* __restrict__ wb) {
  const int n4 = HH * KK / 4;
  const int stride = gridDim.x * blockDim.x;
  for (int i = blockIdx.x * blockDim.x + threadIdx.x; i < n4; i += stride) {
    const float4 v = ((const float4*)w)[i];
    ushort4 o;
    o.x = f2bf(v.x); o.y = f2bf(v.y); o.z = f2bf(v.z); o.w = f2bf(v.w);
    ((ushort4*)wb)[i] = o;
  }
}

// h = gelu( z @ wb^T + fc1_b ), bf16 out.
// m201-style 8-phase schedule adapted: BM=128, BN=256, BK=64, 8 waves (2Mx4N),
// wave-tile 64x64. Tri-buffered LDS (3 K-tile slots, 144 KB), unroll-3 main
// loop = 12 phases. Per phase: ds_read frag subtile -> 1 half-tile stage issue
// -> barrier -> lgkmcnt(0)+sched_barrier -> setprio(1) -> 8 MFMA -> setprio(0)
// -> [vmcnt(7) at group end] -> barrier. Invariant: exactly 7 loads issued
// between a tile's last stage and its first read => vmcnt(7), never a drain.
__global__ __launch_bounds__(512, 1)
void gemm_kernel(const unsigned short* __restrict__ z, const unsigned short* __restrict__ wb,
                 const float* __restrict__ fc1_b, unsigned short* __restrict__ h) {
  __shared__ unsigned short As[3][128 * 64];   // 48 KB
  __shared__ unsigned short Bs[3][256 * 64];   // 96 KB
  const int tid  = threadIdx.x;
  const int lane = tid & 63;
  const int wv   = tid >> 6;       // 0..7
  const int wr   = wv >> 2;        // 0..1 (M)
  const int wc   = wv & 3;         // 0..3 (N)
  // bijective XCD swizzle (256 % 8 == 0); bm fastest within chunk -> each XCD
  // works one 256-col B panel (8MB) while A panels come from L3.
  const int bid = (blockIdx.x & 7) * 32 + (blockIdx.x >> 3);
  const int bm = bid & 31;         // 32 M-tiles of 128
  const int bn = bid >> 5;         // 8 N-tiles of 256

  const int srow   = lane >> 3;            // row-in-8 for staging
  const int schunk = (lane & 7) ^ srow;    // pre-swizzled source 16B chunk
  const int frow = lane & 15;
  const int fkb  = lane >> 4;              // 0..3

  const unsigned short* zb  = z  + (size_t)(bm * 128) * KK;
  const unsigned short* wbb = wb + (size_t)(bn * 256) * KK;

  f32x4 acc[4][4];
  #pragma unroll
  for (int m = 0; m < 4; ++m)
    #pragma unroll
    for (int n = 0; n < 4; ++n)
      acc[m][n] = (f32x4){0.f, 0.f, 0.f, 0.f};

  // A half hh (64 rows, 8KB): 1 load. B half hh (128 rows, 16KB): 2 loads.
  #define STAGE_A(s, u, hh) __builtin_amdgcn_global_load_lds( \
      (const __attribute__((address_space(1))) void*)(zb + (size_t)((hh)*64 + wv*8 + srow) * KK + (size_t)(u)*64 + schunk*8), \
      (__attribute__((address_space(3))) void*)(&As[s][((hh)*64 + wv*8) * 64]), 16, 0, 0)
  #define STAGE_B1(s, u, hh, j) __builtin_amdgcn_global_load_lds( \
      (const __attribute__((address_space(1))) void*)(wbb + (size_t)((hh)*128 + (j)*64 + wv*8 + srow) * KK + (size_t)(u)*64 + schunk*8), \
      (__attribute__((address_space(3))) void*)(&Bs[s][((hh)*128 + (j)*64 + wv*8) * 64]), 16, 0, 0)
  #define STAGE_B(s, u, hh) do { STAGE_B1(s, u, hh, 0); STAGE_B1(s, u, hh, 1); } while (0)

  #define RD_A(S, m_) do { \
    const int Ra = wr*64 + (m_)*16 + frow; \
    af[m_][0] = *reinterpret_cast<const bs8*>(&As[S][Ra*64 + (((fkb) ^ (Ra&7))*8)]); \
    af[m_][1] = *reinterpret_cast<const bs8*>(&As[S][Ra*64 + (((4+fkb) ^ (Ra&7))*8)]); \
  } while (0)
  #define RD_B(S, n_) do { \
    const int Rb = wc*64 + (n_)*16 + frow; \
    bfr[n_][0] = *reinterpret_cast<const bs8*>(&Bs[S][Rb*64 + (((fkb) ^ (Rb&7))*8)]); \
    bfr[n_][1] = *reinterpret_cast<const bs8*>(&Bs[S][Rb*64 + (((4+fkb) ^ (Rb&7))*8)]); \
  } while (0)
  #define MF(m_, n_) do { \
    acc[m_][n_] = __builtin_amdgcn_mfma_f32_16x16x32_bf16(af[m_][0], bfr[n_][0], acc[m_][n_], 0, 0, 0); \
    acc[m_][n_] = __builtin_amdgcn_mfma_f32_16x16x32_bf16(af[m_][1], bfr[n_][1], acc[m_][n_], 0, 0, 0); \
  } while (0)

  #define PH_MID do { __builtin_amdgcn_s_barrier(); \
    asm volatile("s_waitcnt lgkmcnt(0)" ::: "memory"); \
    __builtin_amdgcn_sched_barrier(0); \
    __builtin_amdgcn_s_setprio(1); } while (0)
  #define PH_END do { __builtin_amdgcn_s_setprio(0); \
    __builtin_amdgcn_s_barrier(); } while (0)
  #define PH_ENDW do { __builtin_amdgcn_s_setprio(0); \
    asm volatile("s_waitcnt vmcnt(7)" ::: "memory"); \
    __builtin_amdgcn_s_barrier(); } while (0)

  // Compute slot S (4 phases, 32 MFMA). Stages: ph_a/b/c finish slot S2's
  // next tile uC (A1, B0, B1 — all safe: slot S2's reads retired >=2 phases
  // ago); ph_d starts slot S's own next tile uN (A0 — S's reads retired at
  // ph_c's end barrier).
  #define GROUP(S, S2, uC, uN) do { \
    bs8 af[4][2], bfr[4][2]; \
    RD_A(S, 0); RD_A(S, 1); RD_B(S, 0); RD_B(S, 1); \
    STAGE_A(S2, uC, 1); \
    PH_MID; MF(0,0); MF(0,1); MF(1,0); MF(1,1); PH_END; \
    RD_B(S, 2); RD_B(S, 3); \
    STAGE_B(S2, uC, 0); \
    PH_MID; MF(0,2); MF(0,3); MF(1,2); MF(1,3); PH_END; \
    RD_A(S, 2); RD_A(S, 3); \
    STAGE_B(S2, uC, 1); \
    PH_MID; MF(2,2); MF(2,3); MF(3,2); MF(3,3); PH_END; \
    STAGE_A(S, uN, 0); \
    PH_MID; MF(2,0); MF(2,1); MF(3,0); MF(3,1); PH_ENDW; \
  } while (0)

  // ---- prologue: tile0 -> slot0 (6), tile1 -> slot1 (6), tile2 A0 -> slot2 (1) ----
  STAGE_A(0, 0, 0); STAGE_A(0, 0, 1); STAGE_B(0, 0, 0); STAGE_B(0, 0, 1);
  STAGE_A(1, 1, 0); STAGE_A(1, 1, 1); STAGE_B(1, 1, 0); STAGE_B(1, 1, 1);
  STAGE_A(2, 2, 0);
  asm volatile("s_waitcnt vmcnt(7)" ::: "memory");   // tile0 resident (7 newer in flight)
  __builtin_amdgcn_s_barrier();

  // ---- main loop: 85 iters x 3 K-tiles = tiles 0..254 ----
  for (int t = 0; t < 85; ++t) {
    const int u2 = 3*t + 2;                                // <= 254
    const int u3 = 3*t + 3;                                // <= 255
    const int u4 = (3*t + 4 < NT) ? 3*t + 4 : NT - 1;      // clamp: garbage->slot1, unread
    const int u5 = (3*t + 5 < NT) ? 3*t + 5 : NT - 1;      // clamp: garbage->slot2, unread
    GROUP(0, 2, u2, u3);
    GROUP(1, 0, u3, u4);
    GROUP(2, 1, u4, u5);
  }

  // ---- tail: tile 255 in slot0 (resident via last vmcnt(7)) ----
  {
    bs8 af[4][2], bfr[4][2];
    RD_A(0, 0); RD_A(0, 1); RD_A(0, 2); RD_A(0, 3);
    RD_B(0, 0); RD_B(0, 1); RD_B(0, 2); RD_B(0, 3);
    MF(0,0); MF(0,1); MF(0,2); MF(0,3);
    MF(1,0); MF(1,1); MF(1,2); MF(1,3);
    MF(2,0); MF(2,1); MF(2,2); MF(2,3);
    MF(3,0); MF(3,1); MF(3,2); MF(3,3);
  }
  asm volatile("s_waitcnt vmcnt(0)" ::: "memory");   // drain clamped tail stages

  // ---- epilogue: h = gelu(acc + bias), bf16. C/D: col=lane&15, row=(lane>>4)*4+reg ----
  const int row0 = bm * 128 + wr * 64;
  const int col0 = bn * 256 + wc * 64;
  #pragma unroll
  for (int n = 0; n < 4; ++n) {
    const int col = col0 + n * 16 + frow;
    const float bias = fc1_b[col];
    #pragma unroll
    for (int m = 0; m < 4; ++m) {
      #pragma unroll
      for (int r = 0; r < 4; ++r) {
        const int row = row0 + m * 16 + fkb * 4 + r;
        const float xg = acc[m][n][r] + bias;
        h[(size_t)row * HH + col] = f2bf(0.5f * xg * (1.f + erff(xg * 0.70710678118f)));
      }
    }
  }
  #undef STAGE_A
  #undef STAGE_B1
  #undef STAGE_B
  #undef RD_A
  #undef RD_B
  #undef MF
  #undef PH_MID
  #undef PH_END
  #undef PH_ENDW
  #undef GROUP
}

// out[b] = dot(h[b], hm_w) + hm_b + relu(gamma)*ylin[b];  out[BB+b] = dot(h[b], hv_w) + hv_b
__global__ __launch_bounds__(256)
void head_kernel(const unsigned short* __restrict__ h, const float* __restrict__ hm_w,
                 const float* __restrict__ hm_b, const float* __restrict__ hv_w,
                 const float* __restrict__ hv_b, const float* __restrict__ ylin,
                 const float* __restrict__ gamma, float* __restrict__ out) {
  __shared__ float red[8];
  const int b = blockIdx.x, tid = threadIdx.x;
  const us8 hv8 = ((const us8*)(h + (size_t)b * HH))[tid];
  const float4 m0 = ((const float4*)hm_w)[tid*2],  m1 = ((const float4*)hm_w)[tid*2+1];
  const float4 v0 = ((const float4*)hv_w)[tid*2],  v1 = ((const float4*)hv_w)[tid*2+1];
  float hf[8];
  #pragma unroll
  for (int i = 0; i < 8; ++i) hf[i] = bf2f((unsigned short)hv8[i]);
  float dm = hf[0]*m0.x + hf[1]*m0.y + hf[2]*m0.z + hf[3]*m0.w
           + hf[4]*m1.x + hf[5]*m1.y + hf[6]*m1.z + hf[7]*m1.w;
  float dv = hf[0]*v0.x + hf[1]*v0.y + hf[2]*v0.z + hf[3]*v0.w
           + hf[4]*v1.x + hf[5]*v1.y + hf[6]*v1.z + hf[7]*v1.w;
  #pragma unroll
  for (int off = 32; off > 0; off >>= 1) {
    dm += __shfl_xor(dm, off);
    dv += __shfl_xor(dv, off);
  }
  if ((tid & 63) == 0) { red[(tid>>6)*2] = dm; red[(tid>>6)*2+1] = dv; }
  __syncthreads();
  if (tid == 0) {
    const float sm = red[0]+red[2]+red[4]+red[6] + hm_b[0];
    const float sv = red[1]+red[3]+red[5]+red[7] + hv_b[0];
    out[b]      = sm + fmaxf(gamma[0], 0.f) * ylin[b];
    out[BB + b] = sv;
  }
}

extern "C" void kernel_launch(void* const* d_in, const int* in_sizes, int n_in,
                              void* d_out, int out_size, void* d_ws, size_t ws_size,
                              hipStream_t stream) {
  const float* x       = (const float*)d_in[0];
  const float* ln_g    = (const float*)d_in[1];
  const float* ln_b    = (const float*)d_in[2];
  const float* centers = (const float*)d_in[3];
  const float* width   = (const float*)d_in[4];
  const float* fc1_w   = (const float*)d_in[5];
  const float* fc1_b   = (const float*)d_in[6];
  const float* hm_w    = (const float*)d_in[7];
  const float* hm_b    = (const float*)d_in[8];
  const float* hv_w    = (const float*)d_in[9];
  const float* hv_b    = (const float*)d_in[10];
  const float* sh_w    = (const float*)d_in[11];
  const float* sh_b    = (const float*)d_in[12];
  const float* gamma   = (const float*)d_in[13];

  char* ws = (char*)d_ws;
  // ws layout: cs 64KB @0 | ylin 16KB @64KB | z 128MB @1MB | wb 64MB @129MB | h(bf16) 16MB @193MB
  float* cs            = (float*)(ws);
  float* ylin          = (float*)(ws + (64 << 10));
  unsigned short* z    = (unsigned short*)(ws + (1 << 20));
  unsigned short* wb   = (unsigned short*)(ws + (129ull << 20));
  unsigned short* h    = (unsigned short*)(ws + (193ull << 20));
  float* out           = (float*)d_out;

  prep_kernel<<<dim3(64),   dim3(256), 0, stream>>>(centers, width, cs);
  zexp_kernel<<<dim3(4096), dim3(256), 0, stream>>>(x, ln_g, ln_b, width, sh_w, sh_b, cs, z, ylin);
  cvt_kernel <<<dim3(4096), dim3(256), 0, stream>>>(fc1_w, wb);
  gemm_kernel<<<dim3(256),  dim3(512), 0, stream>>>(z, wb, fc1_b, h);
  head_kernel<<<dim3(4096), dim3(256), 0, stream>>>(h, hm_w, hm_b, hv_w, hv_b, ylin, gamma, out);
}

// Round 6
// 226.595 us; speedup vs baseline: 2.4471x; 2.4471x over previous
//
#include <hip/hip_runtime.h>
#include <hip/hip_bf16.h>

#define BB 4096
#define DD 1024
#define NBF 16
#define HH 2048
#define KK 16384   // DD*NBF (elements; also bytes for i8 rows)
#define LN_EPS 1e-5f

typedef int   i32x4 __attribute__((ext_vector_type(4)));   // i8 MFMA A/B (16 i8) and C/D (4 i32)
typedef float f32x4 __attribute__((ext_vector_type(4)));

__device__ __forceinline__ float softplusf(float x) {
  return (x > 20.f) ? x : log1pf(expf(x));
}
__device__ __forceinline__ int pack4(int q0, int q1, int q2, int q3) {
  return (q0 & 0xff) | ((q1 & 0xff) << 8) | ((q2 & 0xff) << 16) | ((q3 & 0xff) << 24);
}

// cs[d*16+k] = centers[d][k] / (softplus(width[d]) + 1e-6)
__global__ void prep_kernel(const float* __restrict__ centers, const float* __restrict__ width,
                            float* __restrict__ cs) {
  const int i = blockIdx.x * 256 + threadIdx.x;  // 16384 total
  const int d = i >> 4;
  const float w = softplusf(width[d]) + 1e-6f;
  cs[i] = centers[i] / w;
}

// LayerNorm + triangular basis -> zq (i8 [B,KK], zq = round(127*phi)), and ylin[b]
__global__ __launch_bounds__(256)
void zexp_kernel(const float* __restrict__ x, const float* __restrict__ g,
                 const float* __restrict__ be, const float* __restrict__ width,
                 const float* __restrict__ sh_w, const float* __restrict__ sh_b,
                 const float* __restrict__ cs,
                 unsigned char* __restrict__ zq, float* __restrict__ ylin) {
  __shared__ float red[8];
  const int b = blockIdx.x, tid = threadIdx.x;
  const float4 v = ((const float4*)(x + (size_t)b * DD))[tid];
  float s  = v.x + v.y + v.z + v.w;
  float ss = v.x*v.x + v.y*v.y + v.z*v.z + v.w*v.w;
  #pragma unroll
  for (int off = 32; off > 0; off >>= 1) {
    s  += __shfl_xor(s, off);
    ss += __shfl_xor(ss, off);
  }
  if ((tid & 63) == 0) { red[(tid>>6)*2] = s; red[(tid>>6)*2+1] = ss; }
  __syncthreads();
  const float sum   = red[0]+red[2]+red[4]+red[6];
  const float sumsq = red[1]+red[3]+red[5]+red[7];
  const float mu   = sum * (1.f/DD);
  const float var  = sumsq * (1.f/DD) - mu*mu;
  const float rstd = rsqrtf(var + LN_EPS);
  const float4 g4 = ((const float4*)g)[tid];
  const float4 b4 = ((const float4*)be)[tid];
  const float4 w4 = ((const float4*)width)[tid];
  const float4 s4 = ((const float4*)sh_w)[tid];
  const float xn0 = (v.x - mu)*rstd*g4.x + b4.x;
  const float xn1 = (v.y - mu)*rstd*g4.y + b4.y;
  const float xn2 = (v.z - mu)*rstd*g4.z + b4.z;
  const float xn3 = (v.w - mu)*rstd*g4.w + b4.w;
  float xsv[4];
  xsv[0] = xn0 / (softplusf(w4.x) + 1e-6f);
  xsv[1] = xn1 / (softplusf(w4.y) + 1e-6f);
  xsv[2] = xn2 / (softplusf(w4.z) + 1e-6f);
  xsv[3] = xn3 / (softplusf(w4.w) + 1e-6f);
  // thread owns d = tid*4..+3 -> 64 contiguous i8 (16 per d)
  unsigned char* zr = zq + (size_t)b * KK + tid * 64;
  #pragma unroll
  for (int j = 0; j < 4; ++j) {
    const float4* c4 = (const float4*)(cs + (tid * 4 + j) * 16);
    const float xv = xsv[j];
    int q[16];
    #pragma unroll
    for (int qq = 0; qq < 4; ++qq) {
      const float4 ca = c4[qq];
      q[qq*4+0] = __float2int_rn(fmaxf(0.f, 1.f - fabsf(xv - ca.x)) * 127.f);
      q[qq*4+1] = __float2int_rn(fmaxf(0.f, 1.f - fabsf(xv - ca.y)) * 127.f);
      q[qq*4+2] = __float2int_rn(fmaxf(0.f, 1.f - fabsf(xv - ca.z)) * 127.f);
      q[qq*4+3] = __float2int_rn(fmaxf(0.f, 1.f - fabsf(xv - ca.w)) * 127.f);
    }
    int4 o;
    o.x = pack4(q[0],  q[1],  q[2],  q[3]);
    o.y = pack4(q[4],  q[5],  q[6],  q[7]);
    o.z = pack4(q[8],  q[9],  q[10], q[11]);
    o.w = pack4(q[12], q[13], q[14], q[15]);
    ((int4*)zr)[j] = o;
  }
  float yd = xn0*s4.x + xn1*s4.y + xn2*s4.z + xn3*s4.w;
  #pragma unroll
  for (int off = 32; off > 0; off >>= 1) yd += __shfl_xor(yd, off);
  __syncthreads();
  if ((tid & 63) == 0) red[tid>>6] = yd;
  __syncthreads();
  if (tid == 0) ylin[b] = red[0]+red[1]+red[2]+red[3] + sh_b[0];
}

// fc1_w fp32 -> i8 with per-row scale. One block per row j; row held in regs
// (16 float4/thread) so the row is read from HBM exactly once.
__global__ __launch_bounds__(256)
void cvt_kernel(const float* __restrict__ w, unsigned char* __restrict__ wq,
                float* __restrict__ wscale) {
  __shared__ float red[4];
  const int j = blockIdx.x, tid = threadIdx.x;
  const float4* row4 = (const float4*)(w + (size_t)j * KK);
  float4 vv[16];
  float mx = 0.f;
  #pragma unroll
  for (int i = 0; i < 16; ++i) {
    vv[i] = row4[tid + i * 256];
    mx = fmaxf(mx, fmaxf(fmaxf(fabsf(vv[i].x), fabsf(vv[i].y)),
                         fmaxf(fabsf(vv[i].z), fabsf(vv[i].w))));
  }
  #pragma unroll
  for (int off = 32; off > 0; off >>= 1) mx = fmaxf(mx, __shfl_xor(mx, off));
  if ((tid & 63) == 0) red[tid >> 6] = mx;
  __syncthreads();
  const float smax = fmaxf(fmaxf(red[0], red[1]), fmaxf(red[2], red[3]));
  const float inv  = (smax > 0.f) ? 127.f / smax : 0.f;
  if (tid == 0) wscale[j] = smax * (1.f / 127.f);
  int* orow = (int*)(wq + (size_t)j * KK);
  #pragma unroll
  for (int i = 0; i < 16; ++i) {
    const int q0 = __float2int_rn(vv[i].x * inv);
    const int q1 = __float2int_rn(vv[i].y * inv);
    const int q2 = __float2int_rn(vv[i].z * inv);
    const int q3 = __float2int_rn(vv[i].w * inv);
    orow[tid + i * 256] = pack4(q0, q1, q2, q3);
  }
}

// h = gelu( (zq @ wq^T) * scale + fc1_b ), fp32 out.
// R2's proven 2-barrier structure, i8 BK=128: per-iteration identical to R2
// (8 stage loads, 16 ds_read_b128/wave, 32 MFMA/wave, same 128-B-row swizzle)
// but 128 iterations instead of 256. i32 accumulation is exact.
__global__ __launch_bounds__(256, 2)
void gemm_kernel(const unsigned char* __restrict__ zq, const unsigned char* __restrict__ wq,
                 const float* __restrict__ wscale, const float* __restrict__ fc1_b,
                 float* __restrict__ h) {
  __shared__ unsigned char As[128 * 128];   // 16 KB
  __shared__ unsigned char Bs[128 * 128];   // 16 KB
  const int tid  = threadIdx.x;
  const int lane = tid & 63;
  const int wv   = tid >> 6;
  // bijective XCD swizzle (512 % 8 == 0)
  const int bid = (blockIdx.x & 7) * 64 + (blockIdx.x >> 3);
  const int bm = bid & 31;     // M/128 = 32 (fastest -> consecutive blocks share B panel)
  const int bn = bid >> 5;     // N/128 = 16
  const int wr = wv >> 1, wc = wv & 1;

  i32x4 acc[4][4];
  #pragma unroll
  for (int m = 0; m < 4; ++m)
    #pragma unroll
    for (int n = 0; n < 4; ++n)
      acc[m][n] = (i32x4){0, 0, 0, 0};

  const int srow   = lane >> 3;            // row-in-8 for staging
  const int schunk = (lane & 7) ^ srow;    // pre-swizzled source 16B chunk (of 8/row)
  const int frow = lane & 15;
  const int fkb  = lane >> 4;              // 0..3

  const unsigned char* zb  = zq + (size_t)(bm * 128) * KK;
  const unsigned char* wbb = wq + (size_t)(bn * 128) * KK;

  for (int t = 0; t < KK / 128; ++t) {
    const int k0 = t * 128;   // byte offset in row
    __syncthreads();   // previous tile fully consumed
    #pragma unroll
    for (int i = 0; i < 4; ++i) {
      const int r = i * 32 + wv * 8 + srow;
      __builtin_amdgcn_global_load_lds(
          (const __attribute__((address_space(1))) void*)(zb + (size_t)r * KK + k0 + schunk * 16),
          (__attribute__((address_space(3))) void*)(&As[(i * 32 + wv * 8) * 128]), 16, 0, 0);
      __builtin_amdgcn_global_load_lds(
          (const __attribute__((address_space(1))) void*)(wbb + (size_t)r * KK + k0 + schunk * 16),
          (__attribute__((address_space(3))) void*)(&Bs[(i * 32 + wv * 8) * 128]), 16, 0, 0);
    }
    __syncthreads();   // staged (compiler drains vmcnt here)
    #pragma unroll
    for (int ks = 0; ks < 2; ++ks) {
      const int kb = ks * 4 + fkb;     // 16-B chunk index 0..7 within 128-B row
      i32x4 af[4], bfr[4];
      #pragma unroll
      for (int m = 0; m < 4; ++m) {
        const int Ra = wr * 64 + m * 16 + frow;
        af[m] = *reinterpret_cast<const i32x4*>(&As[Ra * 128 + ((kb ^ (Ra & 7)) * 16)]);
      }
      #pragma unroll
      for (int n = 0; n < 4; ++n) {
        const int Rb = wc * 64 + n * 16 + frow;
        bfr[n] = *reinterpret_cast<const i32x4*>(&Bs[Rb * 128 + ((kb ^ (Rb & 7)) * 16)]);
      }
      #pragma unroll
      for (int m = 0; m < 4; ++m)
        #pragma unroll
        for (int n = 0; n < 4; ++n)
          acc[m][n] = __builtin_amdgcn_mfma_i32_16x16x64_i8(af[m], bfr[n], acc[m][n], 0, 0, 0);
    }
  }
  // epilogue: h = gelu(acc * (wscale[col]/127) + bias), fp32.
  // C/D: col=lane&15, row=(lane>>4)*4+reg
  const int row0 = bm * 128 + wr * 64;
  const int col0 = bn * 128 + wc * 64;
  #pragma unroll
  for (int n = 0; n < 4; ++n) {
    const int col = col0 + n * 16 + frow;
    const float sc   = wscale[col] * (1.f / 127.f);
    const float bias = fc1_b[col];
    #pragma unroll
    for (int m = 0; m < 4; ++m) {
      #pragma unroll
      for (int r = 0; r < 4; ++r) {
        const int row = row0 + m * 16 + fkb * 4 + r;
        const float xg = (float)acc[m][n][r] * sc + bias;
        h[(size_t)row * HH + col] = 0.5f * xg * (1.f + erff(xg * 0.70710678118f));
      }
    }
  }
}

// out[b] = dot(h[b], hm_w) + hm_b + relu(gamma)*ylin[b];  out[BB+b] = dot(h[b], hv_w) + hv_b
__global__ __launch_bounds__(256)
void head_kernel(const float* __restrict__ h, const float* __restrict__ hm_w,
                 const float* __restrict__ hm_b, const float* __restrict__ hv_w,
                 const float* __restrict__ hv_b, const float* __restrict__ ylin,
                 const float* __restrict__ gamma, float* __restrict__ out) {
  __shared__ float red[8];
  const int b = blockIdx.x, tid = threadIdx.x;
  const float4* hr  = (const float4*)(h + (size_t)b * HH);
  const float4* wm  = (const float4*)hm_w;
  const float4* wvv = (const float4*)hv_w;
  float dm = 0.f, dv = 0.f;
  #pragma unroll
  for (int i = 0; i < 2; ++i) {
    const int c = tid + i * 256;
    const float4 hv4 = hr[c];
    const float4 m4  = wm[c];
    const float4 v4  = wvv[c];
    dm += hv4.x*m4.x + hv4.y*m4.y + hv4.z*m4.z + hv4.w*m4.w;
    dv += hv4.x*v4.x + hv4.y*v4.y + hv4.z*v4.z + hv4.w*v4.w;
  }
  #pragma unroll
  for (int off = 32; off > 0; off >>= 1) {
    dm += __shfl_xor(dm, off);
    dv += __shfl_xor(dv, off);
  }
  if ((tid & 63) == 0) { red[(tid>>6)*2] = dm; red[(tid>>6)*2+1] = dv; }
  __syncthreads();
  if (tid == 0) {
    const float sm = red[0]+red[2]+red[4]+red[6] + hm_b[0];
    const float sv = red[1]+red[3]+red[5]+red[7] + hv_b[0];
    out[b]      = sm + fmaxf(gamma[0], 0.f) * ylin[b];
    out[BB + b] = sv;
  }
}

extern "C" void kernel_launch(void* const* d_in, const int* in_sizes, int n_in,
                              void* d_out, int out_size, void* d_ws, size_t ws_size,
                              hipStream_t stream) {
  const float* x       = (const float*)d_in[0];
  const float* ln_g    = (const float*)d_in[1];
  const float* ln_b    = (const float*)d_in[2];
  const float* centers = (const float*)d_in[3];
  const float* width   = (const float*)d_in[4];
  const float* fc1_w   = (const float*)d_in[5];
  const float* fc1_b   = (const float*)d_in[6];
  const float* hm_w    = (const float*)d_in[7];
  const float* hm_b    = (const float*)d_in[8];
  const float* hv_w    = (const float*)d_in[9];
  const float* hv_b    = (const float*)d_in[10];
  const float* sh_w    = (const float*)d_in[11];
  const float* sh_b    = (const float*)d_in[12];
  const float* gamma   = (const float*)d_in[13];

  char* ws = (char*)d_ws;
  // ws: cs 64KB @0 | ylin 16KB @64KB | wscale 8KB @80KB | zq 64MB @1MB | wq 32MB @65MB | h(f32) 32MB @97MB
  float* cs            = (float*)(ws);
  float* ylin          = (float*)(ws + (64 << 10));
  float* wscale        = (float*)(ws + (80 << 10));
  unsigned char* zq    = (unsigned char*)(ws + (1ull << 20));
  unsigned char* wq    = (unsigned char*)(ws + (65ull << 20));
  float* h             = (float*)(ws + (97ull << 20));
  float* out           = (float*)d_out;

  prep_kernel<<<dim3(64),   dim3(256), 0, stream>>>(centers, width, cs);
  zexp_kernel<<<dim3(4096), dim3(256), 0, stream>>>(x, ln_g, ln_b, width, sh_w, sh_b, cs, zq, ylin);
  cvt_kernel <<<dim3(2048), dim3(256), 0, stream>>>(fc1_w, wq, wscale);
  gemm_kernel<<<dim3(512),  dim3(256), 0, stream>>>(zq, wq, wscale, fc1_b, h);
  head_kernel<<<dim3(4096), dim3(256), 0, stream>>>(h, hm_w, hm_b, hv_w, hv_b, ylin, gamma, out);
}

// Round 7
// 223.879 us; speedup vs baseline: 2.4768x; 1.0121x over previous
//
#include <hip/hip_runtime.h>
#include <hip/hip_bf16.h>

#define BB 4096
#define DD 1024
#define NBF 16
#define HH 2048
#define KK 16384   // DD*NBF (elements; also bytes for i8 rows)
#define LN_EPS 1e-5f

typedef int   i32x4 __attribute__((ext_vector_type(4)));   // i8 MFMA A/B (16 i8) and C/D (4 i32)
typedef unsigned short us8 __attribute__((ext_vector_type(8)));

__device__ __forceinline__ unsigned short f2bf(float f) {
  union { float f; unsigned int u; } c; c.f = f;
  unsigned int u = c.u;
  return (unsigned short)((u + 0x7FFFu + ((u >> 16) & 1u)) >> 16);  // RNE
}
__device__ __forceinline__ float bf2f(unsigned short s) {
  union { unsigned int u; float f; } c; c.u = ((unsigned int)s) << 16;
  return c.f;
}
__device__ __forceinline__ float softplusf(float x) {
  return (x > 20.f) ? x : log1pf(expf(x));
}
__device__ __forceinline__ int pack4(int q0, int q1, int q2, int q3) {
  return (q0 & 0xff) | ((q1 & 0xff) << 8) | ((q2 & 0xff) << 16) | ((q3 & 0xff) << 24);
}

// cs[d*16+k] = centers[d][k] / (softplus(width[d]) + 1e-6)
__global__ void prep_kernel(const float* __restrict__ centers, const float* __restrict__ width,
                            float* __restrict__ cs) {
  const int i = blockIdx.x * 256 + threadIdx.x;  // 16384 total
  const int d = i >> 4;
  const float w = softplusf(width[d]) + 1e-6f;
  cs[i] = centers[i] / w;
}

// LayerNorm + triangular basis -> zq (i8 [B,KK], zq = round(127*phi)), and ylin[b]
__global__ __launch_bounds__(256)
void zexp_kernel(const float* __restrict__ x, const float* __restrict__ g,
                 const float* __restrict__ be, const float* __restrict__ width,
                 const float* __restrict__ sh_w, const float* __restrict__ sh_b,
                 const float* __restrict__ cs,
                 unsigned char* __restrict__ zq, float* __restrict__ ylin) {
  __shared__ float red[8];
  const int b = blockIdx.x, tid = threadIdx.x;
  const float4 v = ((const float4*)(x + (size_t)b * DD))[tid];
  float s  = v.x + v.y + v.z + v.w;
  float ss = v.x*v.x + v.y*v.y + v.z*v.z + v.w*v.w;
  #pragma unroll
  for (int off = 32; off > 0; off >>= 1) {
    s  += __shfl_xor(s, off);
    ss += __shfl_xor(ss, off);
  }
  if ((tid & 63) == 0) { red[(tid>>6)*2] = s; red[(tid>>6)*2+1] = ss; }
  __syncthreads();
  const float sum   = red[0]+red[2]+red[4]+red[6];
  const float sumsq = red[1]+red[3]+red[5]+red[7];
  const float mu   = sum * (1.f/DD);
  const float var  = sumsq * (1.f/DD) - mu*mu;
  const float rstd = rsqrtf(var + LN_EPS);
  const float4 g4 = ((const float4*)g)[tid];
  const float4 b4 = ((const float4*)be)[tid];
  const float4 w4 = ((const float4*)width)[tid];
  const float4 s4 = ((const float4*)sh_w)[tid];
  const float xn0 = (v.x - mu)*rstd*g4.x + b4.x;
  const float xn1 = (v.y - mu)*rstd*g4.y + b4.y;
  const float xn2 = (v.z - mu)*rstd*g4.z + b4.z;
  const float xn3 = (v.w - mu)*rstd*g4.w + b4.w;
  float xsv[4];
  xsv[0] = xn0 / (softplusf(w4.x) + 1e-6f);
  xsv[1] = xn1 / (softplusf(w4.y) + 1e-6f);
  xsv[2] = xn2 / (softplusf(w4.z) + 1e-6f);
  xsv[3] = xn3 / (softplusf(w4.w) + 1e-6f);
  // thread owns d = tid*4..+3 -> 64 contiguous i8 (16 per d)
  unsigned char* zr = zq + (size_t)b * KK + tid * 64;
  #pragma unroll
  for (int j = 0; j < 4; ++j) {
    const float4* c4 = (const float4*)(cs + (tid * 4 + j) * 16);
    const float xv = xsv[j];
    int q[16];
    #pragma unroll
    for (int qq = 0; qq < 4; ++qq) {
      const float4 ca = c4[qq];
      q[qq*4+0] = __float2int_rn(fmaxf(0.f, 1.f - fabsf(xv - ca.x)) * 127.f);
      q[qq*4+1] = __float2int_rn(fmaxf(0.f, 1.f - fabsf(xv - ca.y)) * 127.f);
      q[qq*4+2] = __float2int_rn(fmaxf(0.f, 1.f - fabsf(xv - ca.z)) * 127.f);
      q[qq*4+3] = __float2int_rn(fmaxf(0.f, 1.f - fabsf(xv - ca.w)) * 127.f);
    }
    int4 o;
    o.x = pack4(q[0],  q[1],  q[2],  q[3]);
    o.y = pack4(q[4],  q[5],  q[6],  q[7]);
    o.z = pack4(q[8],  q[9],  q[10], q[11]);
    o.w = pack4(q[12], q[13], q[14], q[15]);
    ((int4*)zr)[j] = o;
  }
  float yd = xn0*s4.x + xn1*s4.y + xn2*s4.z + xn3*s4.w;
  #pragma unroll
  for (int off = 32; off > 0; off >>= 1) yd += __shfl_xor(yd, off);
  __syncthreads();
  if ((tid & 63) == 0) red[tid>>6] = yd;
  __syncthreads();
  if (tid == 0) ylin[b] = red[0]+red[1]+red[2]+red[3] + sh_b[0];
}

// fc1_w fp32 -> i8 with per-row scale. One block per row j; row held in regs.
__global__ __launch_bounds__(256)
void cvt_kernel(const float* __restrict__ w, unsigned char* __restrict__ wq,
                float* __restrict__ wscale) {
  __shared__ float red[4];
  const int j = blockIdx.x, tid = threadIdx.x;
  const float4* row4 = (const float4*)(w + (size_t)j * KK);
  float4 vv[16];
  float mx = 0.f;
  #pragma unroll
  for (int i = 0; i < 16; ++i) {
    vv[i] = row4[tid + i * 256];
    mx = fmaxf(mx, fmaxf(fmaxf(fabsf(vv[i].x), fabsf(vv[i].y)),
                         fmaxf(fabsf(vv[i].z), fabsf(vv[i].w))));
  }
  #pragma unroll
  for (int off = 32; off > 0; off >>= 1) mx = fmaxf(mx, __shfl_xor(mx, off));
  if ((tid & 63) == 0) red[tid >> 6] = mx;
  __syncthreads();
  const float smax = fmaxf(fmaxf(red[0], red[1]), fmaxf(red[2], red[3]));
  const float inv  = (smax > 0.f) ? 127.f / smax : 0.f;
  if (tid == 0) wscale[j] = smax * (1.f / 127.f);
  int* orow = (int*)(wq + (size_t)j * KK);
  #pragma unroll
  for (int i = 0; i < 16; ++i) {
    const int q0 = __float2int_rn(vv[i].x * inv);
    const int q1 = __float2int_rn(vv[i].y * inv);
    const int q2 = __float2int_rn(vv[i].z * inv);
    const int q3 = __float2int_rn(vv[i].w * inv);
    orow[tid + i * 256] = pack4(q0, q1, q2, q3);
  }
}

// h = gelu( (zq @ wq^T) * scale + fc1_b ), bf16 out.
// i8 BK=128, 128x128 tile, 4 waves of 64x64, i32 accumulation (exact).
// DOUBLE-buffered LDS, ONE __syncthreads() per K-iter:
//   syncthreads (drains tile t's loads, issued last iter, ~full compute ago)
//   -> issue tile t+1 stage into buf^1 -> ds_read+MFMA from buf.
// The staging latency now hides under compute instead of being drained
// immediately after issue (R6's exposed-latency stall).
__global__ __launch_bounds__(256, 2)
void gemm_kernel(const unsigned char* __restrict__ zq, const unsigned char* __restrict__ wq,
                 const float* __restrict__ wscale, const float* __restrict__ fc1_b,
                 unsigned short* __restrict__ h) {
  __shared__ unsigned char As[2][128 * 128];   // 32 KB
  __shared__ unsigned char Bs[2][128 * 128];   // 32 KB
  const int tid  = threadIdx.x;
  const int lane = tid & 63;
  const int wv   = tid >> 6;
  // bijective XCD swizzle (512 % 8 == 0)
  const int bid = (blockIdx.x & 7) * 64 + (blockIdx.x >> 3);
  const int bm = bid & 31;     // M/128 = 32 (fastest -> consecutive blocks share B panel)
  const int bn = bid >> 5;     // N/128 = 16
  const int wr = wv >> 1, wc = wv & 1;

  i32x4 acc[4][4];
  #pragma unroll
  for (int m = 0; m < 4; ++m)
    #pragma unroll
    for (int n = 0; n < 4; ++n)
      acc[m][n] = (i32x4){0, 0, 0, 0};

  const int srow   = lane >> 3;            // row-in-8 for staging
  const int schunk = (lane & 7) ^ srow;    // pre-swizzled source 16B chunk (of 8/row)
  const int frow = lane & 15;
  const int fkb  = lane >> 4;              // 0..3

  const unsigned char* zb  = zq + (size_t)(bm * 128) * KK;
  const unsigned char* wbb = wq + (size_t)(bn * 128) * KK;

  #define STAGE(buf, t) do { \
    const int k0_ = (t) * 128; \
    _Pragma("unroll") \
    for (int i_ = 0; i_ < 4; ++i_) { \
      const int r_ = i_ * 32 + wv * 8 + srow; \
      __builtin_amdgcn_global_load_lds( \
          (const __attribute__((address_space(1))) void*)(zb + (size_t)r_ * KK + k0_ + schunk * 16), \
          (__attribute__((address_space(3))) void*)(&As[buf][(i_ * 32 + wv * 8) * 128]), 16, 0, 0); \
      __builtin_amdgcn_global_load_lds( \
          (const __attribute__((address_space(1))) void*)(wbb + (size_t)r_ * KK + k0_ + schunk * 16), \
          (__attribute__((address_space(3))) void*)(&Bs[buf][(i_ * 32 + wv * 8) * 128]), 16, 0, 0); \
    } \
  } while (0)

  STAGE(0, 0);   // prologue: tile 0 into buf 0

  for (int t = 0; t < KK / 128; ++t) {
    __syncthreads();   // drains vmcnt: tile t resident; buf[(t+1)&1] reads retired
    if (t + 1 < KK / 128) STAGE((t + 1) & 1, t + 1);
    const unsigned char* Ac = &As[t & 1][0];
    const unsigned char* Bc = &Bs[t & 1][0];
    #pragma unroll
    for (int ks = 0; ks < 2; ++ks) {
      const int kb = ks * 4 + fkb;     // 16-B chunk index 0..7 within 128-B row
      i32x4 af[4], bfr[4];
      #pragma unroll
      for (int m = 0; m < 4; ++m) {
        const int Ra = wr * 64 + m * 16 + frow;
        af[m] = *reinterpret_cast<const i32x4*>(&Ac[Ra * 128 + ((kb ^ (Ra & 7)) * 16)]);
      }
      #pragma unroll
      for (int n = 0; n < 4; ++n) {
        const int Rb = wc * 64 + n * 16 + frow;
        bfr[n] = *reinterpret_cast<const i32x4*>(&Bc[Rb * 128 + ((kb ^ (Rb & 7)) * 16)]);
      }
      #pragma unroll
      for (int m = 0; m < 4; ++m)
        #pragma unroll
        for (int n = 0; n < 4; ++n)
          acc[m][n] = __builtin_amdgcn_mfma_i32_16x16x64_i8(af[m], bfr[n], acc[m][n], 0, 0, 0);
    }
  }
  #undef STAGE

  // epilogue: h = gelu(acc * (wscale[col]/127) + bias), bf16.
  // C/D: col=lane&15, row=(lane>>4)*4+reg
  const int row0 = bm * 128 + wr * 64;
  const int col0 = bn * 128 + wc * 64;
  #pragma unroll
  for (int n = 0; n < 4; ++n) {
    const int col = col0 + n * 16 + frow;
    const float sc   = wscale[col] * (1.f / 127.f);
    const float bias = fc1_b[col];
    #pragma unroll
    for (int m = 0; m < 4; ++m) {
      #pragma unroll
      for (int r = 0; r < 4; ++r) {
        const int row = row0 + m * 16 + fkb * 4 + r;
        const float xg = (float)acc[m][n][r] * sc + bias;
        h[(size_t)row * HH + col] = f2bf(0.5f * xg * (1.f + erff(xg * 0.70710678118f)));
      }
    }
  }
}

// out[b] = dot(h[b], hm_w) + hm_b + relu(gamma)*ylin[b];  out[BB+b] = dot(h[b], hv_w) + hv_b
__global__ __launch_bounds__(256)
void head_kernel(const unsigned short* __restrict__ h, const float* __restrict__ hm_w,
                 const float* __restrict__ hm_b, const float* __restrict__ hv_w,
                 const float* __restrict__ hv_b, const float* __restrict__ ylin,
                 const float* __restrict__ gamma, float* __restrict__ out) {
  __shared__ float red[8];
  const int b = blockIdx.x, tid = threadIdx.x;
  const us8 hv8 = ((const us8*)(h + (size_t)b * HH))[tid];
  const float4 m0 = ((const float4*)hm_w)[tid*2],  m1 = ((const float4*)hm_w)[tid*2+1];
  const float4 v0 = ((const float4*)hv_w)[tid*2],  v1 = ((const float4*)hv_w)[tid*2+1];
  float hf[8];
  #pragma unroll
  for (int i = 0; i < 8; ++i) hf[i] = bf2f((unsigned short)hv8[i]);
  float dm = hf[0]*m0.x + hf[1]*m0.y + hf[2]*m0.z + hf[3]*m0.w
           + hf[4]*m1.x + hf[5]*m1.y + hf[6]*m1.z + hf[7]*m1.w;
  float dv = hf[0]*v0.x + hf[1]*v0.y + hf[2]*v0.z + hf[3]*v0.w
           + hf[4]*v1.x + hf[5]*v1.y + hf[6]*v1.z + hf[7]*v1.w;
  #pragma unroll
  for (int off = 32; off > 0; off >>= 1) {
    dm += __shfl_xor(dm, off);
    dv += __shfl_xor(dv, off);
  }
  if ((tid & 63) == 0) { red[(tid>>6)*2] = dm; red[(tid>>6)*2+1] = dv; }
  __syncthreads();
  if (tid == 0) {
    const float sm = red[0]+red[2]+red[4]+red[6] + hm_b[0];
    const float sv = red[1]+red[3]+red[5]+red[7] + hv_b[0];
    out[b]      = sm + fmaxf(gamma[0], 0.f) * ylin[b];
    out[BB + b] = sv;
  }
}

extern "C" void kernel_launch(void* const* d_in, const int* in_sizes, int n_in,
                              void* d_out, int out_size, void* d_ws, size_t ws_size,
                              hipStream_t stream) {
  const float* x       = (const float*)d_in[0];
  const float* ln_g    = (const float*)d_in[1];
  const float* ln_b    = (const float*)d_in[2];
  const float* centers = (const float*)d_in[3];
  const float* width   = (const float*)d_in[4];
  const float* fc1_w   = (const float*)d_in[5];
  const float* fc1_b   = (const float*)d_in[6];
  const float* hm_w    = (const float*)d_in[7];
  const float* hm_b    = (const float*)d_in[8];
  const float* hv_w    = (const float*)d_in[9];
  const float* hv_b    = (const float*)d_in[10];
  const float* sh_w    = (const float*)d_in[11];
  const float* sh_b    = (const float*)d_in[12];
  const float* gamma   = (const float*)d_in[13];

  char* ws = (char*)d_ws;
  // ws: cs 64KB @0 | ylin 16KB @64KB | wscale 8KB @80KB | zq 64MB @1MB | wq 32MB @65MB | h(bf16) 16MB @97MB
  float* cs            = (float*)(ws);
  float* ylin          = (float*)(ws + (64 << 10));
  float* wscale        = (float*)(ws + (80 << 10));
  unsigned char* zq    = (unsigned char*)(ws + (1ull << 20));
  unsigned char* wq    = (unsigned char*)(ws + (65ull << 20));
  unsigned short* h    = (unsigned short*)(ws + (97ull << 20));
  float* out           = (float*)d_out;

  prep_kernel<<<dim3(64),   dim3(256), 0, stream>>>(centers, width, cs);
  zexp_kernel<<<dim3(4096), dim3(256), 0, stream>>>(x, ln_g, ln_b, width, sh_w, sh_b, cs, zq, ylin);
  cvt_kernel <<<dim3(2048), dim3(256), 0, stream>>>(fc1_w, wq, wscale);
  gemm_kernel<<<dim3(512),  dim3(256), 0, stream>>>(zq, wq, wscale, fc1_b, h);
  head_kernel<<<dim3(4096), dim3(256), 0, stream>>>(h, hm_w, hm_b, hv_w, hv_b, ylin, gamma, out);
}